// Round 4
// baseline (97.060 us; speedup 1.0000x reference)
//
#include <hip/hip_runtime.h>
#include <hip/hip_bf16.h>

typedef float f2 __attribute__((ext_vector_type(2)));
typedef float f4 __attribute__((ext_vector_type(4)));

constexpr int Hh = 224, Ww = 224, Bb = 8, Kc = 4, RAD = 5;

// 256 threads: tx(32) x ty(4) x half(2). Each thread: 2 vertical centers,
// but only HALF of the 12-row shared window (rows half*6 .. half*6+5).
// The two halves' partial sums merge for free in the block reduction.
constexpr int TX = 32;
constexpr int TILEH = 8;              // center rows per block
constexpr int SW = TX + 2 * RAD;      // 42
constexpr int SH = TILEH + 2 * RAD;   // 18
constexpr int SSTR = SW + 1;          // 43 (odd -> conflict-free; col 42 = pad)
constexpr int GXD = Ww / TX;          // 7
constexpr int GYD = Hh / TILEH;       // 28
constexpr int PB = GXD * GYD;         // 196 blocks per batch image

constexpr float LOG2E = 1.44269504f;
constexpr float KI  = -0.01f * LOG2E;     // intensity coeff (exp2 domain)
constexpr float DSC = -0.0625f * LOG2E;   // distance coeff  (exp2 domain)

static __device__ inline f4 splat4(float x) { return (f4){x, x, x, x}; }

__global__ __launch_bounds__(256, 6) void ncut_main(const float* __restrict__ images,
                                                    const float* __restrict__ labels,
                                                    float* __restrict__ acc) {
    __shared__ float simg[SH * SSTR];   // 3.1 KB
    __shared__ f4    slab[SH * SSTR];   // 12.4 KB
    __shared__ float red[4][8];

    const int b   = blockIdx.z;
    const int x0  = blockIdx.x * TX;
    const int y0  = blockIdx.y * TILEH;
    const int tid = threadIdx.x;

    const float* imgb = images + (size_t)b * (Hh * Ww);
    const float* labb = labels + (size_t)b * (Kc * Hh * Ww);

    // Stage tile + halo (incl. stride-pad column as OOB).
    // OOB: img = 1e19 -> weight underflows to exactly 0; labels = 0.
    for (int idx = tid; idx < SH * SSTR; idx += 256) {
        const int lx = idx % SSTR, ly = idx / SSTR;
        const int gx = x0 - RAD + lx, gy = y0 - RAD + ly;
        float iv = 1e19f;
        f4 lv = (f4){0.f, 0.f, 0.f, 0.f};
        if (lx < SW && gx >= 0 && gx < Ww && gy >= 0 && gy < Hh) {
            const int g = gy * Ww + gx;
            iv = imgb[g] * 255.0f;
            lv = (f4){labb[g], labb[Hh * Ww + g], labb[2 * Hh * Ww + g], labb[3 * Hh * Ww + g]};
        }
        simg[idx] = iv;
        slab[idx] = lv;
    }
    __syncthreads();

    const int tx   = tid & 31;
    const int ty   = (tid >> 5) & 3;   // 0..3 -> center tile rows 2ty, 2ty+1
    const int half = tid >> 7;         // wave-uniform: waves 0,1 -> 0; waves 2,3 -> 1
    const int r0   = 2 * ty;           // top LDS row of the 12-row window

    const float c0 = simg[(r0 + RAD) * SSTR + tx + RAD];
    const float c1 = simg[(r0 + RAD + 1) * SSTR + tx + RAD];

    f4 num0 = splat4(0.f), num1 = splat4(0.f);
    f2 den0 = (f2){0.f, 0.f}, den1 = (f2){0.f, 0.f};

#pragma unroll
    for (int r = 0; r < 6; ++r) {
        const int dr = half * 6 + r;          // wave-uniform row index in [0,12)
        const int rowoff = (r0 + dr) * SSTR + tx;
        // y-distance factors (wave-uniform, branch-free masking of the
        // 1 inactive row-center combo per half: dr=0/c1 and dr=11/c0)
        const int   di0 = dr - 5,        di1 = dr - 6;
        const float fd0 = (float)(di0 * di0), fd1 = (float)(di1 * di1);
        const float dyw0 = (fd0 <= 25.f) ? __builtin_amdgcn_exp2f(fd0 * DSC) : 0.f;
        const float dyw1 = (fd1 <= 25.f) ? __builtin_amdgcn_exp2f(fd1 * DSC) : 0.f;
#pragma unroll
        for (int i = 0; i < 6; ++i) {
            const f2 v  = (f2){simg[rowoff + 2 * i], simg[rowoff + 2 * i + 1]};
            const f4 p0 = slab[rowoff + 2 * i];
            const f4 p1 = slab[rowoff + 2 * i + 1];
            // dx^2 immediates; col 11 (i=5,.y) is the stride-pad col: its
            // staged img=1e19 already forces w=0, dxt value irrelevant.
            const f2 dxt = (f2){(float)((2 * i - 5) * (2 * i - 5)) * DSC,
                                (float)((2 * i - 4) * (2 * i - 4)) * DSC};
            {
                const f2 d = v - c0;
                const f2 t = __builtin_elementwise_fma(d * KI, d, dxt);
                const float w0 = __builtin_amdgcn_exp2f(t.x) * dyw0;
                const float w1 = __builtin_amdgcn_exp2f(t.y) * dyw0;
                den0 += (f2){w0, w1};
                num0 = __builtin_elementwise_fma(splat4(w0), p0, num0);
                num0 = __builtin_elementwise_fma(splat4(w1), p1, num0);
            }
            {
                const f2 d = v - c1;
                const f2 t = __builtin_elementwise_fma(d * KI, d, dxt);
                const float w0 = __builtin_amdgcn_exp2f(t.x) * dyw1;
                const float w1 = __builtin_amdgcn_exp2f(t.y) * dyw1;
                den1 += (f2){w0, w1};
                num1 = __builtin_elementwise_fma(splat4(w0), p0, num1);
                num1 = __builtin_elementwise_fma(splat4(w1), p1, num1);
            }
        }
    }

    const f4 pc0 = slab[(r0 + RAD) * SSTR + tx + RAD];
    const f4 pc1 = slab[(r0 + RAD + 1) * SSTR + tx + RAD];

    const f4 numv = pc0 * num0 + pc1 * num1;
    const f4 denv = pc0 * (den0.x + den0.y) + pc1 * (den1.x + den1.y);

    float vals[8] = {numv.x, numv.y, numv.z, numv.w, denv.x, denv.y, denv.z, denv.w};

#pragma unroll
    for (int i = 0; i < 8; ++i) {
        float v = vals[i];
#pragma unroll
        for (int off = 32; off > 0; off >>= 1) v += __shfl_down(v, off, 64);
        vals[i] = v;
    }

    const int wave = tid >> 6, lane = tid & 63;
    if (lane == 0) {
#pragma unroll
        for (int i = 0; i < 8; ++i) red[wave][i] = vals[i];
    }
    __syncthreads();

    if (tid < 8) {
        const int gid = blockIdx.x + GXD * blockIdx.y + PB * blockIdx.z;
        acc[gid * 8 + tid] = red[0][tid] + red[1][tid] + red[2][tid] + red[3][tid];
    }
}

__global__ void ncut_final(const float* __restrict__ acc, float* __restrict__ out) {
    __shared__ float part[64];
    const int t = threadIdx.x;              // 256
    const int combo = t >> 2;               // 0..63 : b(3b) | idx(3b)
    const int sub   = t & 3;
    const int b   = combo >> 3;
    const int idx = combo & 7;
    float s = 0.f;
    for (int j = sub; j < PB; j += 4) s += acc[((size_t)(b * PB + j)) * 8 + idx];
    s += __shfl_down(s, 2, 64);
    s += __shfl_down(s, 1, 64);
    if (sub == 0) part[combo] = s;
    __syncthreads();
    if (t < 64) {
        float r = 0.f;
        if (t < 32) {
            const int bb = t >> 2, k = t & 3;
            r = fabsf(part[(bb << 3) + k] / part[(bb << 3) + 4 + k]);
        }
#pragma unroll
        for (int off = 32; off > 0; off >>= 1) r += __shfl_down(r, off, 64);
        if (t == 0) out[0] = (float)Kc - r * (1.0f / (float)Bb);
    }
}

extern "C" void kernel_launch(void* const* d_in, const int* in_sizes, int n_in,
                              void* d_out, int out_size, void* d_ws, size_t ws_size,
                              hipStream_t stream) {
    const float* images = (const float*)d_in[0];
    const float* labels = (const float*)d_in[1];
    float* out = (float*)d_out;
    float* acc = (float*)d_ws;   // 1568 blocks * 8 partials, fully overwritten

    dim3 grid(GXD, GYD, Bb);     // 7 x 28 x 8 = 1568 blocks
    ncut_main<<<grid, 256, 0, stream>>>(images, labels, acc);
    ncut_final<<<1, 256, 0, stream>>>(acc, out);
}

// Round 5
// 87.819 us; speedup vs baseline: 1.1052x; 1.1052x over previous
//
#include <hip/hip_runtime.h>
#include <hip/hip_bf16.h>

typedef float    f2 __attribute__((ext_vector_type(2)));
typedef float    f4 __attribute__((ext_vector_type(4)));
typedef _Float16 h4 __attribute__((ext_vector_type(4)));

constexpr int Hh = 224, Ww = 224, Bb = 8, Kc = 4, RAD = 5;

// R2-proven geometry: 784 blocks, 256 threads, 2 vertical centers/thread.
constexpr int TX = 32;
constexpr int TILEH = 16;
constexpr int SW = TX + 2 * RAD;      // 42
constexpr int SH = TILEH + 2 * RAD;   // 26
constexpr int SSTR = SW + 1;          // 43 (odd; col 42 = pad column)
constexpr int GXD = Ww / TX;          // 7
constexpr int GYD = Hh / TILEH;       // 14
constexpr int PB = GXD * GYD;         // 98 blocks per batch image
constexpr int NB = PB * Bb;           // 784 total blocks

constexpr float LOG2E = 1.44269504f;
constexpr float KI  = -0.01f * LOG2E;     // intensity coeff (exp2 domain)
constexpr float DSC = -0.0625f * LOG2E;   // distance coeff  (exp2 domain)
// e^{-d^2/16}, d = 0..5 (row-distance factors, applied per row-partial)
constexpr float DYW[6] = {1.0f, 0.93941306f, 0.77880078f,
                          0.56978282f, 0.36787944f, 0.20961139f};
// dx^2 per column offset j = 0..10; j = 11 is the pairing pad (forced w=0)
constexpr float DX2[12] = {25.f,16.f,9.f,4.f,1.f,0.f,1.f,4.f,9.f,16.f,25.f,0.f};

static __device__ inline f4 splat4(float x) { return (f4){x, x, x, x}; }
static __device__ inline f4 cvt4(h4 q) {
    return (f4){(float)q.x, (float)q.y, (float)q.z, (float)q.w};
}

__global__ __launch_bounds__(256, 3) void ncut_main(const float* __restrict__ images,
                                                    const float* __restrict__ labels,
                                                    float* __restrict__ acc) {
    // simgB[k] = simgA[k+1]: shifted copy so every lane's column pair is an
    // aligned 8B ds_read_b64 regardless of address parity.
    __shared__ __align__(16) float simgA[SH * SSTR];
    __shared__ __align__(16) float simgB[SH * SSTR];
    __shared__ __align__(16) h4    slab[SH * SSTR];    // fp16 labels: 8B/px
    __shared__ float red[4][8];

    const int b   = blockIdx.z;
    const int x0  = blockIdx.x * TX;
    const int y0  = blockIdx.y * TILEH;
    const int tid = threadIdx.x;

    const float* imgb = images + (size_t)b * (Hh * Ww);
    const float* labb = labels + (size_t)b * (Kc * Hh * Ww);

    // Stage tile + halo (incl. stride-pad column). OOB: img = 1e19 -> weight
    // underflows to exactly 0; labels = 0.
    for (int idx = tid; idx < SH * SSTR; idx += 256) {
        const int lx = idx % SSTR, ly = idx / SSTR;
        const int gx = x0 - RAD + lx, gy = y0 - RAD + ly;
        float iv = 1e19f;
        h4 lv = (h4){(_Float16)0.f, (_Float16)0.f, (_Float16)0.f, (_Float16)0.f};
        if (lx < SW && gx >= 0 && gx < Ww && gy >= 0 && gy < Hh) {
            const int g = gy * Ww + gx;
            iv = imgb[g] * 255.0f;
            lv = (h4){(_Float16)labb[g],
                      (_Float16)labb[Hh * Ww + g],
                      (_Float16)labb[2 * Hh * Ww + g],
                      (_Float16)labb[3 * Hh * Ww + g]};
        }
        simgA[idx] = iv;
        if (idx > 0) simgB[idx - 1] = iv;
        slab[idx] = lv;
    }
    __syncthreads();

    const int tx = tid & 31;
    const int ty = tid >> 5;      // 0..7
    const int r0 = 2 * ty;        // top LDS row of this thread's 12-row window

    const float c0 = simgA[(r0 + RAD) * SSTR + tx + RAD];
    const float c1 = simgA[(r0 + RAD + 1) * SSTR + tx + RAD];

    f4 num0 = splat4(0.f), num1 = splat4(0.f);
    f2 den0 = (f2){0.f, 0.f}, den1 = (f2){0.f, 0.f};

#pragma unroll
    for (int dr = 0; dr < 12; ++dr) {
        const int rowi   = r0 + dr;
        const int rowoff = rowi * SSTR + tx;
        const int par    = (rowi + tx) & 1;          // parity of rowoff (43 odd)
        const float* sb  = par ? simgB : simgA;
        const int a0     = rowoff - par;             // even -> aligned b64

        f4 nr0 = splat4(0.f), nr1 = splat4(0.f);     // row partials (dy-factor deferred)
        f2 dn0 = (f2){0.f, 0.f}, dn1 = (f2){0.f, 0.f};

#pragma unroll
        for (int i = 0; i < 6; ++i) {
            const f2 v  = *(const f2*)&sb[a0 + 2 * i];
            const f4 p0 = cvt4(slab[rowoff + 2 * i]);
            const f4 p1 = cvt4(slab[rowoff + 2 * i + 1]);
            const f2 dxt = (f2){DX2[2 * i] * DSC,
                                (2 * i + 1 == 11) ? -1e38f : DX2[2 * i + 1] * DSC};
            if (dr != 11) {  // center0 active for dr = 0..10
                const f2 d = v - c0;
                const f2 t = __builtin_elementwise_fma(d * KI, d, dxt);
                const float w0 = __builtin_amdgcn_exp2f(t.x);
                const float w1 = __builtin_amdgcn_exp2f(t.y);
                dn0 += (f2){w0, w1};
                nr0 = __builtin_elementwise_fma(splat4(w0), p0, nr0);
                nr0 = __builtin_elementwise_fma(splat4(w1), p1, nr0);
            }
            if (dr != 0) {   // center1 active for dr = 1..11
                const f2 d = v - c1;
                const f2 t = __builtin_elementwise_fma(d * KI, d, dxt);
                const float w0 = __builtin_amdgcn_exp2f(t.x);
                const float w1 = __builtin_amdgcn_exp2f(t.y);
                dn1 += (f2){w0, w1};
                nr1 = __builtin_elementwise_fma(splat4(w0), p0, nr1);
                nr1 = __builtin_elementwise_fma(splat4(w1), p1, nr1);
            }
        }
        // Apply exact row-distance factor once per row (two-exp form).
        if (dr != 11) {
            const int  ad = (dr < 5) ? 5 - dr : dr - 5;
            const float y = DYW[ad];
            num0 = __builtin_elementwise_fma(splat4(y), nr0, num0);
            den0 = __builtin_elementwise_fma((f2){y, y}, dn0, den0);
        }
        if (dr != 0) {
            const int  ad = (dr < 6) ? 6 - dr : dr - 6;
            const float y = DYW[ad];
            num1 = __builtin_elementwise_fma(splat4(y), nr1, num1);
            den1 = __builtin_elementwise_fma((f2){y, y}, dn1, den1);
        }
    }

    const f4 pc0 = cvt4(slab[(r0 + RAD) * SSTR + tx + RAD]);
    const f4 pc1 = cvt4(slab[(r0 + RAD + 1) * SSTR + tx + RAD]);

    const f4 numv = pc0 * num0 + pc1 * num1;
    const f4 denv = pc0 * (den0.x + den0.y) + pc1 * (den1.x + den1.y);

    float vals[8] = {numv.x, numv.y, numv.z, numv.w, denv.x, denv.y, denv.z, denv.w};

#pragma unroll
    for (int i = 0; i < 8; ++i) {
        float v = vals[i];
#pragma unroll
        for (int off = 32; off > 0; off >>= 1) v += __shfl_down(v, off, 64);
        vals[i] = v;
    }

    const int wave = tid >> 6, lane = tid & 63;
    if (lane == 0) {
#pragma unroll
        for (int i = 0; i < 8; ++i) red[wave][i] = vals[i];
    }
    __syncthreads();

    if (tid < 8) {
        const int gid = blockIdx.x + GXD * blockIdx.y + PB * blockIdx.z;
        // transposed layout: [idx][gid] -> contiguous per (idx,b) for the final
        acc[tid * NB + gid] = red[0][tid] + red[1][tid] + red[2][tid] + red[3][tid];
    }
}

__global__ void ncut_final(const float* __restrict__ acc, float* __restrict__ out) {
    __shared__ float part[64];
    const int t = threadIdx.x;            // 1024
    const int combo = t >> 4;             // 0..63 = idx*8 + b
    const int sub   = t & 15;
    const int idx = combo >> 3, b = combo & 7;
    const float* p = acc + idx * NB + b * PB;   // 98 contiguous partials
    float s = 0.f;
    for (int j = sub; j < PB; j += 16) s += p[j];
    s += __shfl_down(s, 8, 64);
    s += __shfl_down(s, 4, 64);
    s += __shfl_down(s, 2, 64);
    s += __shfl_down(s, 1, 64);
    if (sub == 0) part[combo] = s;
    __syncthreads();
    if (t < 64) {
        float r = 0.f;
        if (t < 32) {
            const int k = t & 3, bb = t >> 2;
            r = fabsf(part[k * 8 + bb] / part[(k + 4) * 8 + bb]);
        }
#pragma unroll
        for (int off = 32; off > 0; off >>= 1) r += __shfl_down(r, off, 64);
        if (t == 0) out[0] = (float)Kc - r * (1.0f / (float)Bb);
    }
}

extern "C" void kernel_launch(void* const* d_in, const int* in_sizes, int n_in,
                              void* d_out, int out_size, void* d_ws, size_t ws_size,
                              hipStream_t stream) {
    const float* images = (const float*)d_in[0];
    const float* labels = (const float*)d_in[1];
    float* out = (float*)d_out;
    float* acc = (float*)d_ws;   // 8 * 784 floats, fully overwritten each launch

    dim3 grid(GXD, GYD, Bb);     // 7 x 14 x 8 = 784 blocks
    ncut_main<<<grid, 256, 0, stream>>>(images, labels, acc);
    ncut_final<<<1, 1024, 0, stream>>>(acc, out);
}

// Round 6
// 85.605 us; speedup vs baseline: 1.1338x; 1.0259x over previous
//
#include <hip/hip_runtime.h>
#include <hip/hip_bf16.h>

typedef float f2 __attribute__((ext_vector_type(2)));
typedef float f4 __attribute__((ext_vector_type(4)));

constexpr int Hh = 224, Ww = 224, Bb = 8, Kc = 4, RAD = 5;

// R2's proven per-thread work (2 vertical centers, one-exp form) with
// finer grid granularity: 128-thread blocks, 32x8 tile -> 1568 blocks
// = 6.12 blocks/CU (load-balance tail 14% vs R2's 33%).
constexpr int TX = 32;
constexpr int TILEH = 8;
constexpr int SW = TX + 2 * RAD;      // 42
constexpr int SH = TILEH + 2 * RAD;   // 18
constexpr int SSTR = SW + 1;          // 43 (odd -> conflict-free; col 42 = pad)
constexpr int GXD = Ww / TX;          // 7
constexpr int GYD = Hh / TILEH;       // 28
constexpr int PB = GXD * GYD;         // 196 blocks per batch image
constexpr int NB = PB * Bb;           // 1568 total blocks

constexpr float LOG2E = 1.44269504f;
constexpr float KI  = -0.01f * LOG2E;     // intensity coeff (exp2 domain)
constexpr float DSC = -0.0625f * LOG2E;   // distance coeff  (exp2 domain)
// d^2 per kernel offset; index 11 is the pad column (weight forced to 0)
constexpr float D2[12] = {25.f,16.f,9.f,4.f,1.f,0.f,1.f,4.f,9.f,16.f,25.f,0.f};

static __device__ inline f4 splat4(float x) { return (f4){x, x, x, x}; }

__global__ __launch_bounds__(128, 3) void ncut_main(const float* __restrict__ images,
                                                    const float* __restrict__ labels,
                                                    float* __restrict__ acc) {
    __shared__ float simg[SH * SSTR];   // 3.1 KB
    __shared__ f4    slab[SH * SSTR];   // 12.4 KB
    __shared__ float red[2][8];

    const int b   = blockIdx.z;
    const int x0  = blockIdx.x * TX;
    const int y0  = blockIdx.y * TILEH;
    const int tid = threadIdx.x;

    const float* imgb = images + (size_t)b * (Hh * Ww);
    const float* labb = labels + (size_t)b * (Kc * Hh * Ww);

    // Stage tile + halo (incl. stride-pad column as OOB).
    // OOB: img = 1e19 -> weight underflows to exactly 0; labels = 0.
    for (int idx = tid; idx < SH * SSTR; idx += 128) {
        const int lx = idx % SSTR, ly = idx / SSTR;
        const int gx = x0 - RAD + lx, gy = y0 - RAD + ly;
        float iv = 1e19f;
        f4 lv = (f4){0.f, 0.f, 0.f, 0.f};
        if (lx < SW && gx >= 0 && gx < Ww && gy >= 0 && gy < Hh) {
            const int g = gy * Ww + gx;
            iv = imgb[g] * 255.0f;
            lv = (f4){labb[g], labb[Hh * Ww + g], labb[2 * Hh * Ww + g], labb[3 * Hh * Ww + g]};
        }
        simg[idx] = iv;
        slab[idx] = lv;
    }
    __syncthreads();

    const int tx = tid & 31;
    const int ty = tid >> 5;      // 0..3
    const int r0 = 2 * ty;        // top LDS row of this thread's 12-row window

    const float c0 = simg[(r0 + RAD) * SSTR + tx + RAD];
    const float c1 = simg[(r0 + RAD + 1) * SSTR + tx + RAD];

    f4 num0 = splat4(0.f), num1 = splat4(0.f);
    f2 den0 = (f2){0.f, 0.f}, den1 = (f2){0.f, 0.f};

    // 12 rows: row dr serves center0 (dy=dr, dr<11) and center1 (dy=dr-1, dr>=1)
#pragma unroll
    for (int dr = 0; dr < 12; ++dr) {
        const int rowoff = (r0 + dr) * SSTR + tx;
#pragma unroll
        for (int i = 0; i < 6; ++i) {
            const f2 v  = (f2){simg[rowoff + 2 * i], simg[rowoff + 2 * i + 1]};
            const f4 p0 = slab[rowoff + 2 * i];
            const f4 p1 = slab[rowoff + 2 * i + 1];
            if (dr < 11) {
                const f2 base = (f2){(D2[2 * i] + D2[dr]) * DSC,
                                     (D2[2 * i + 1] + D2[dr]) * DSC};
                const f2 d = v - c0;
                const f2 a = __builtin_elementwise_fma(d * KI, d, base);
                const float e0 = __builtin_amdgcn_exp2f(a.x);
                const float e1 = __builtin_amdgcn_exp2f(a.y);
                den0 += (f2){e0, e1};
                num0 = __builtin_elementwise_fma(splat4(e0), p0, num0);
                num0 = __builtin_elementwise_fma(splat4(e1), p1, num0);
            }
            if (dr >= 1) {
                const f2 base = (f2){(D2[2 * i] + D2[dr - 1]) * DSC,
                                     (D2[2 * i + 1] + D2[dr - 1]) * DSC};
                const f2 d = v - c1;
                const f2 a = __builtin_elementwise_fma(d * KI, d, base);
                const float e0 = __builtin_amdgcn_exp2f(a.x);
                const float e1 = __builtin_amdgcn_exp2f(a.y);
                den1 += (f2){e0, e1};
                num1 = __builtin_elementwise_fma(splat4(e0), p0, num1);
                num1 = __builtin_elementwise_fma(splat4(e1), p1, num1);
            }
        }
    }

    const f4 pc0 = slab[(r0 + RAD) * SSTR + tx + RAD];
    const f4 pc1 = slab[(r0 + RAD + 1) * SSTR + tx + RAD];

    const f4 numv = pc0 * num0 + pc1 * num1;
    const f4 denv = pc0 * (den0.x + den0.y) + pc1 * (den1.x + den1.y);

    float vals[8] = {numv.x, numv.y, numv.z, numv.w, denv.x, denv.y, denv.z, denv.w};

#pragma unroll
    for (int i = 0; i < 8; ++i) {
        float v = vals[i];
#pragma unroll
        for (int off = 32; off > 0; off >>= 1) v += __shfl_down(v, off, 64);
        vals[i] = v;
    }

    const int wave = tid >> 6, lane = tid & 63;
    if (lane == 0) {
#pragma unroll
        for (int i = 0; i < 8; ++i) red[wave][i] = vals[i];
    }
    __syncthreads();

    if (tid < 8) {
        const int gid = blockIdx.x + GXD * blockIdx.y + PB * blockIdx.z;
        // transposed layout: [idx][gid] -> contiguous per (idx,b) for the final
        acc[tid * NB + gid] = red[0][tid] + red[1][tid];
    }
}

__global__ void ncut_final(const float* __restrict__ acc, float* __restrict__ out) {
    __shared__ float part[64];
    const int t = threadIdx.x;            // 1024
    const int combo = t >> 4;             // 0..63 = idx*8 + b
    const int sub   = t & 15;
    const int idx = combo >> 3, b = combo & 7;
    const float* p = acc + idx * NB + b * PB;   // 196 contiguous partials
    float s = 0.f;
    for (int j = sub; j < PB; j += 16) s += p[j];
    s += __shfl_down(s, 8, 64);
    s += __shfl_down(s, 4, 64);
    s += __shfl_down(s, 2, 64);
    s += __shfl_down(s, 1, 64);
    if (sub == 0) part[combo] = s;
    __syncthreads();
    if (t < 64) {
        float r = 0.f;
        if (t < 32) {
            const int k = t & 3, bb = t >> 2;
            r = fabsf(part[k * 8 + bb] / part[(k + 4) * 8 + bb]);
        }
#pragma unroll
        for (int off = 32; off > 0; off >>= 1) r += __shfl_down(r, off, 64);
        if (t == 0) out[0] = (float)Kc - r * (1.0f / (float)Bb);
    }
}

extern "C" void kernel_launch(void* const* d_in, const int* in_sizes, int n_in,
                              void* d_out, int out_size, void* d_ws, size_t ws_size,
                              hipStream_t stream) {
    const float* images = (const float*)d_in[0];
    const float* labels = (const float*)d_in[1];
    float* out = (float*)d_out;
    float* acc = (float*)d_ws;   // 8 * 1568 floats, fully overwritten each launch

    dim3 grid(GXD, GYD, Bb);     // 7 x 28 x 8 = 1568 blocks
    ncut_main<<<grid, 128, 0, stream>>>(images, labels, acc);
    ncut_final<<<1, 1024, 0, stream>>>(acc, out);
}

// Round 7
// 84.392 us; speedup vs baseline: 1.1501x; 1.0144x over previous
//
#include <hip/hip_runtime.h>
#include <hip/hip_bf16.h>

typedef float f2 __attribute__((ext_vector_type(2)));
typedef float f4 __attribute__((ext_vector_type(4)));

constexpr int Hh = 224, Ww = 224, Bb = 8, Kc = 4, RAD = 5;

// Best-measured configuration (R2, 84.0 us): 256 threads = 32x8, each thread
// computes 2 vertically-adjacent centers -> 32x16 tile, 784 blocks.
// Six rounds of perturbation experiments (occupancy, reg-cap, LDS halving,
// grid granularity) all regressed: this sits at the VALU-issue floor
// (~48.6M center-neighbor ops x ~9 slots / 64 lanes / 1024 SIMDs ~= 5.6 us)
// against a ~75.5 us fixed harness poison/restore overhead.
constexpr int TX = 32;
constexpr int TILEH = 16;
constexpr int SW = TX + 2 * RAD;      // 42
constexpr int SH = TILEH + 2 * RAD;   // 26
constexpr int SSTR = SW + 1;          // 43 (odd -> conflict-free; col 42 = pad column)
constexpr int GXD = Ww / TX;          // 7
constexpr int GYD = Hh / TILEH;       // 14
constexpr int PB = GXD * GYD;         // 98 blocks per batch image

constexpr float LOG2E = 1.44269504f;
constexpr float KI  = -0.01f * LOG2E;     // intensity coeff (exp2 domain)
constexpr float DSC = -0.0625f * LOG2E;   // distance coeff  (exp2 domain)
// d^2 per kernel offset; index 11 is the pad column (value irrelevant, weight = 0)
constexpr float D2[12] = {25.f,16.f,9.f,4.f,1.f,0.f,1.f,4.f,9.f,16.f,25.f,0.f};

static __device__ inline f4 splat4(float x) { return (f4){x, x, x, x}; }

__global__ __launch_bounds__(256, 3) void ncut_main(const float* __restrict__ images,
                                                    const float* __restrict__ labels,
                                                    float* __restrict__ acc) {
    __shared__ float simg[SH * SSTR];
    __shared__ f4    slab[SH * SSTR];
    __shared__ float red[4][8];

    const int b   = blockIdx.z;
    const int x0  = blockIdx.x * TX;
    const int y0  = blockIdx.y * TILEH;
    const int tid = threadIdx.x;

    const float* imgb = images + (size_t)b * (Hh * Ww);
    const float* labb = labels + (size_t)b * (Kc * Hh * Ww);

    // Stage tile + halo (incl. the stride-pad column as OOB).
    // OOB: img = 1e19 -> single-exp weight underflows to exactly 0; labels = 0.
    for (int idx = tid; idx < SH * SSTR; idx += 256) {
        const int lx = idx % SSTR, ly = idx / SSTR;
        const int gx = x0 - RAD + lx, gy = y0 - RAD + ly;
        float iv = 1e19f;
        f4 lv = (f4){0.f, 0.f, 0.f, 0.f};
        if (lx < SW && gx >= 0 && gx < Ww && gy >= 0 && gy < Hh) {
            const int g = gy * Ww + gx;
            iv = imgb[g] * 255.0f;
            lv = (f4){labb[g], labb[Hh * Ww + g], labb[2 * Hh * Ww + g], labb[3 * Hh * Ww + g]};
        }
        simg[idx] = iv;
        slab[idx] = lv;
    }
    __syncthreads();

    const int tx = tid & 31;
    const int ty = tid >> 5;      // 0..7
    const int r0 = 2 * ty;        // top LDS row of this thread's 12-row window

    const float c0 = simg[(r0 + RAD) * SSTR + tx + RAD];
    const float c1 = simg[(r0 + RAD + 1) * SSTR + tx + RAD];

    f4 num0 = splat4(0.f), num1 = splat4(0.f);
    f2 den0 = (f2){0.f, 0.f}, den1 = (f2){0.f, 0.f};

    // 12 rows: row dr serves center0 (dy=dr, dr<11) and center1 (dy=dr-1, dr>=1)
#pragma unroll
    for (int dr = 0; dr < 12; ++dr) {
        const int rowoff = (r0 + dr) * SSTR + tx;
#pragma unroll
        for (int i = 0; i < 6; ++i) {
            const f2 v  = (f2){simg[rowoff + 2 * i], simg[rowoff + 2 * i + 1]};
            const f4 p0 = slab[rowoff + 2 * i];
            const f4 p1 = slab[rowoff + 2 * i + 1];
            if (dr < 11) {
                const f2 base = (f2){(D2[2 * i] + D2[dr]) * DSC,
                                     (D2[2 * i + 1] + D2[dr]) * DSC};
                const f2 d = v - c0;
                const f2 a = __builtin_elementwise_fma(d * KI, d, base);
                const float e0 = __builtin_amdgcn_exp2f(a.x);
                const float e1 = __builtin_amdgcn_exp2f(a.y);
                den0 += (f2){e0, e1};
                num0 = __builtin_elementwise_fma(splat4(e0), p0, num0);
                num0 = __builtin_elementwise_fma(splat4(e1), p1, num0);
            }
            if (dr >= 1) {
                const f2 base = (f2){(D2[2 * i] + D2[dr - 1]) * DSC,
                                     (D2[2 * i + 1] + D2[dr - 1]) * DSC};
                const f2 d = v - c1;
                const f2 a = __builtin_elementwise_fma(d * KI, d, base);
                const float e0 = __builtin_amdgcn_exp2f(a.x);
                const float e1 = __builtin_amdgcn_exp2f(a.y);
                den1 += (f2){e0, e1};
                num1 = __builtin_elementwise_fma(splat4(e0), p0, num1);
                num1 = __builtin_elementwise_fma(splat4(e1), p1, num1);
            }
        }
    }

    const f4 pc0 = slab[(r0 + RAD) * SSTR + tx + RAD];
    const f4 pc1 = slab[(r0 + RAD + 1) * SSTR + tx + RAD];
    const float dn0 = den0.x + den0.y;
    const float dn1 = den1.x + den1.y;

    const f4 numv = pc0 * num0 + pc1 * num1;                 // per-class sum p_f * num
    const f4 denv = pc0 * dn0 + pc1 * dn1;                   // per-class sum p_f * den

    float vals[8] = {numv.x, numv.y, numv.z, numv.w, denv.x, denv.y, denv.z, denv.w};

#pragma unroll
    for (int i = 0; i < 8; ++i) {
        float v = vals[i];
#pragma unroll
        for (int off = 32; off > 0; off >>= 1) v += __shfl_down(v, off, 64);
        vals[i] = v;
    }

    const int wave = tid >> 6, lane = tid & 63;
    if (lane == 0) {
#pragma unroll
        for (int i = 0; i < 8; ++i) red[wave][i] = vals[i];
    }
    __syncthreads();

    if (tid < 8) {
        const int gid = blockIdx.x + GXD * blockIdx.y + GXD * GYD * blockIdx.z;
        acc[gid * 8 + tid] = red[0][tid] + red[1][tid] + red[2][tid] + red[3][tid];
    }
}

__global__ void ncut_final(const float* __restrict__ acc, float* __restrict__ out) {
    const int t = threadIdx.x;          // 64
    const int k = t & 3, b = (t >> 2) & 7, part = t >> 5;
    float s = 0.f;
    for (int j = 0; j < PB; ++j) s += acc[(b * PB + j) * 8 + k + 4 * part];
    const float den = __shfl(s, (t + 32) & 63, 64);
    float r = (t < 32) ? fabsf(s / den) : 0.f;
#pragma unroll
    for (int off = 32; off > 0; off >>= 1) r += __shfl_down(r, off, 64);
    if (t == 0) out[0] = (float)Kc - r * (1.0f / (float)Bb);
}

extern "C" void kernel_launch(void* const* d_in, const int* in_sizes, int n_in,
                              void* d_out, int out_size, void* d_ws, size_t ws_size,
                              hipStream_t stream) {
    const float* images = (const float*)d_in[0];
    const float* labels = (const float*)d_in[1];
    float* out = (float*)d_out;
    float* acc = (float*)d_ws;  // PB*Bb blocks * 8 partials, fully overwritten each launch

    dim3 grid(GXD, GYD, Bb);    // 7 x 14 x 8
    ncut_main<<<grid, 256, 0, stream>>>(images, labels, acc);
    ncut_final<<<1, 64, 0, stream>>>(acc, out);
}